// Round 9
// baseline (1952.426 us; speedup 1.0000x reference)
//
#include <hip/hip_runtime.h>
#include <hip/hip_bf16.h>

// Problem constants: B=128, N=1024, E=16384, ENTITY=100000, EMB=100, HID=100

typedef unsigned int u32;
typedef short short8 __attribute__((ext_vector_type(8)));   // 8 bf16 (4 VGPR)
typedef float f32x4 __attribute__((ext_vector_type(4)));    // MFMA acc

__device__ __forceinline__ float bflo(u32 u) {
    union { u32 i; float f; } v; v.i = u << 16; return v.f;
}
__device__ __forceinline__ float bfhi(u32 u) {
    union { u32 i; float f; } v; v.i = u & 0xffff0000u; return v.f;
}
__device__ __forceinline__ u32 f2bf1(float f) {
    union { float f; u32 u; } v; v.f = f;
    return (v.u + 0x7fffu + ((v.u >> 16) & 1u)) >> 16;   // RNE
}
__device__ __forceinline__ u32 packbf(float a, float b) {
    return f2bf1(a) | (f2bf1(b) << 16);
}
__device__ __forceinline__ float sigm(float x) { return 1.f / (1.f + __expf(-x)); }
__device__ __forceinline__ float tanh_fast(float x) {
    float e = __expf(2.f * x);
    return 1.f - 2.f / (e + 1.f);
}

// ---------------------------------------------------------------------------
// Kernel 1: embedding gather + GCN matmul.  support[n][h] (bf16 packed u32)
// ---------------------------------------------------------------------------
__global__ __launch_bounds__(256, 2)
void gcn_kernel(const int* __restrict__ nb, const float* __restrict__ emb,
                const float* __restrict__ w, u32* __restrict__ support)
{
    __shared__ float wl[10000];
    for (int i = threadIdx.x; i < 10000; i += 256) wl[i] = w[i];
    __syncthreads();

    const int n = blockIdx.x * 256 + threadIdx.x;
    const long long row = nb[n];
    const float4* __restrict__ xr = (const float4*)(emb + row * 100);

    float acc[100];
#pragma unroll
    for (int h = 0; h < 100; ++h) acc[h] = 0.f;

    for (int kk = 0; kk < 25; ++kk) {
        const float4 xv = xr[kk];
        const float xs[4] = { xv.x, xv.y, xv.z, xv.w };
#pragma unroll
        for (int q = 0; q < 4; ++q) {
            const float* wrow = &wl[(kk * 4 + q) * 100];
            const float xq = xs[q];
#pragma unroll
            for (int h4 = 0; h4 < 25; ++h4) {
                const float4 w4 = *(const float4*)(wrow + h4 * 4);
                acc[h4*4+0] = fmaf(xq, w4.x, acc[h4*4+0]);
                acc[h4*4+1] = fmaf(xq, w4.y, acc[h4*4+1]);
                acc[h4*4+2] = fmaf(xq, w4.z, acc[h4*4+2]);
                acc[h4*4+3] = fmaf(xq, w4.w, acc[h4*4+3]);
            }
        }
    }

    u32* __restrict__ o = support + (size_t)n * 50;
#pragma unroll
    for (int i = 0; i < 50; ++i) o[i] = packbf(acc[2*i], acc[2*i+1]);
}

// ---------------------------------------------------------------------------
// Kernel 2a: per-sample counting-sort into CSR order (r6 race fix included).
// ---------------------------------------------------------------------------
__global__ __launch_bounds__(256, 2)
void csr_build(const int* __restrict__ arow, const int* __restrict__ acol,
               const float* __restrict__ aval,
               int* __restrict__ offs, int2* __restrict__ csr)
{
    __shared__ int cnt[1024];
    __shared__ int part[256];
    __shared__ int offl[1024];

    const int b   = blockIdx.x;
    const int tid = threadIdx.x;
    const int*   rw = arow + b * 16384;
    const int*   cl = acol + b * 16384;
    const float* vl = aval + b * 16384;

    for (int i = tid; i < 1024; i += 256) cnt[i] = 0;
    __syncthreads();
    for (int e = tid; e < 16384; e += 256) atomicAdd(&cnt[rw[e]], 1);
    __syncthreads();

    int c[4]; int s = 0;
#pragma unroll
    for (int q = 0; q < 4; ++q) { c[q] = cnt[tid * 4 + q]; s += c[q]; }
    part[tid] = s;
    __syncthreads();
    for (int off = 1; off < 256; off <<= 1) {
        int v = (tid >= off) ? part[tid - off] : 0;
        __syncthreads();
        part[tid] += v;
        __syncthreads();
    }
    int run = part[tid] - s;
#pragma unroll
    for (int q = 0; q < 4; ++q) { offl[tid * 4 + q] = run; run += c[q]; }
    __syncthreads();

    for (int i = tid; i < 1024; i += 256) offs[b * 1025 + i] = offl[i];
    if (tid == 0) offs[b * 1025 + 1024] = 16384;
    __syncthreads();                       // race fix (r6)

    int2* cs = csr + (size_t)b * 16384;
    for (int e = tid; e < 16384; e += 256) {
        const int r   = rw[e];
        const int pos = atomicAdd(&offl[r], 1);
        int2 cv; cv.x = cl[e]; cv.y = __float_as_int(vl[e]);
        cs[pos] = cv;
    }
}

// ---------------------------------------------------------------------------
// Kernel 2b: atomic-free CSR aggregate.  50 lanes/row.
// ---------------------------------------------------------------------------
__global__ __launch_bounds__(256, 4)
void spmm_agg(const int* __restrict__ offs, const int2* __restrict__ csr,
              const u32* __restrict__ support,
              const float* __restrict__ gcn_b, u32* __restrict__ seq)
{
    const int b    = blockIdx.y;
    const int lr   = threadIdx.x / 50;
    const int lane = threadIdx.x % 50;
    const int r    = blockIdx.x * 5 + lr;
    if (lr >= 5 || r >= 1024) return;

    const int e0 = offs[b * 1025 + r];
    const int e1 = offs[b * 1025 + r + 1];
    const int2* __restrict__ cs = csr + (size_t)b * 16384;
    const u32* __restrict__ supb = support + (size_t)b * 1024 * 50;

    float a0 = 0.f, a1 = 0.f;
    for (int e = e0; e < e1; ++e) {
        const int2 cv = cs[e];
        const float v = __int_as_float(cv.y);
        const u32 u = supb[(size_t)cv.x * 50 + lane];
        a0 = fmaf(v, bflo(u), a0);
        a1 = fmaf(v, bfhi(u), a1);
    }
    a0 += gcn_b[2 * lane];
    a1 += gcn_b[2 * lane + 1];
    seq[((size_t)b * 1024 + r) * 50 + lane] = packbf(a0, a1);
}

// ---------------------------------------------------------------------------
// Kernel 3: gx GEMM.  gx[m][g*50+jw] packs units (2jw,2jw+1) of gate g, bf16.
// ---------------------------------------------------------------------------
__global__ __launch_bounds__(256, 2)
void gx_gemm0(const u32* __restrict__ seq, const float* __restrict__ w_ih,
              const float* __restrict__ b_ih, u32* __restrict__ gxW,
              int c0, int ctl, int CT)
{
    __shared__ float wl[10000];
    const int g    = blockIdx.x % 3;
    const int tile = blockIdx.x / 3;
    const int tid  = threadIdx.x;

    for (int i = tid; i < 10000; i += 256)
        wl[(i % 100) * 100 + (i / 100)] = w_ih[g * 10000 + i];   // transpose
    __syncthreads();

    const int m = tile * 256 + tid;              // 0 .. 128*CT-1
    const int b = m >> ctl;
    const int t = m & (CT - 1);
    const uint2* sr2 = (const uint2*)(seq + ((size_t)b * 1024 + c0 + t) * 50);

    float acc[100];
    const float4* bi4 = (const float4*)(b_ih + g * 100);
#pragma unroll
    for (int j4 = 0; j4 < 25; ++j4) {
        const float4 bv = bi4[j4];
        acc[j4*4+0] = bv.x; acc[j4*4+1] = bv.y; acc[j4*4+2] = bv.z; acc[j4*4+3] = bv.w;
    }

    for (int kk = 0; kk < 25; ++kk) {
        const uint2 up = sr2[kk];
        const float xs[4] = { bflo(up.x), bfhi(up.x), bflo(up.y), bfhi(up.y) };
#pragma unroll
        for (int q = 0; q < 4; ++q) {
            const float* wrow = &wl[(kk * 4 + q) * 100];
            const float xq = xs[q];
#pragma unroll
            for (int j4 = 0; j4 < 25; ++j4) {
                const float4 w4 = *(const float4*)(wrow + j4 * 4);
                acc[j4*4+0] = fmaf(xq, w4.x, acc[j4*4+0]);
                acc[j4*4+1] = fmaf(xq, w4.y, acc[j4*4+1]);
                acc[j4*4+2] = fmaf(xq, w4.z, acc[j4*4+2]);
                acc[j4*4+3] = fmaf(xq, w4.w, acc[j4*4+3]);
            }
        }
    }

    u32* og = gxW + (size_t)m * 150 + g * 50;
#pragma unroll
    for (int i = 0; i < 50; ++i) og[i] = packbf(acc[2*i], acc[2*i+1]);
}

// ---------------------------------------------------------------------------
// Kernel 4 (MFMA): GRU recurrence.  16 blocks x 8 samples, 7 waves (448 thr).
// Wave w owns gate-units [16w,16w+16).  Per step: 4 ds_read_b128 A-frags
// (h bf16, LDS ping-pong, row-padded to 136 u16 -> 2-way-free banks),
// 12 mfma_f32_16x16x32_bf16 (3 gates x 4 K-iters) with W_hh held as
// loop-invariant B-fragments in 48 VGPRs.  C/D layout (col=lane&15=unit,
// row=quad*4+reg=sample) puts r/z/n of a (sample,unit) in the SAME lane:
// gate epilogue entirely in registers, h_old in 4 regs, 4 ds_write_b16,
// ONE barrier/step.  gx: 12 b32 loads, prefetch distance 2.
// Layouts per m89 (C/D), m118/m120 (A: m=lane&15, k=quad*8+j; B dual).
// ---------------------------------------------------------------------------
__global__ __attribute__((amdgpu_waves_per_eu(1, 2))) __launch_bounds__(448, 1)
void gru_mfma(const u32* __restrict__ gxR, int CT,
              const float* __restrict__ w_hh, const float* __restrict__ b_hh,
              float* __restrict__ hg, const float* __restrict__ fc1_w,
              const float* __restrict__ fc1_b, float* __restrict__ out,
              int first, int last)
{
    __shared__ unsigned short hA[2][16][136];    // [buf][sample][k], 8704 B

    const int tid  = threadIdx.x;
    const int wave = tid >> 6;
    const int lane = tid & 63;
    const int col  = lane & 15;
    const int quad = lane >> 4;
    const int u    = wave * 16 + col;            // unit 0..111 (>=100 pad)
    const int uc   = (u < 100) ? u : 0;
    const int s0   = blockIdx.x * 8;
    const int sl   = quad * 4;                   // sample-local base of D rows
    const bool epi = (quad < 2) && (u < 100);    // lanes owning real (s,u)
    const int odd  = u & 1;

    // zero both h buffers (incl. pad rows 8..15 and pad cols 100..135)
    for (int i = tid; i < 2 * 16 * 136; i += 448) ((unsigned short*)hA)[i] = 0;

    // ---- loop-invariant B-fragments: W_hh -> bf16, 3 gates x 4 K-iters ----
    short8 bfr[3][4];
#pragma unroll
    for (int g = 0; g < 3; ++g)
#pragma unroll
        for (int ki = 0; ki < 4; ++ki) {
            short8 v;
#pragma unroll
            for (int j = 0; j < 8; ++j) {
                const int k = ki * 32 + quad * 8 + j;
                const float wv = (u < 100 && k < 100)
                               ? w_hh[(size_t)(g * 100 + u) * 100 + k] : 0.f;
                v[j] = (short)f2bf1(wv);
            }
            bfr[g][ki] = v;
        }
    float bh0 = b_hh[uc], bh1 = b_hh[100 + uc], bh2 = b_hh[200 + uc];

    float h_old[4] = {0.f, 0.f, 0.f, 0.f};
    if (epi && !first) {
#pragma unroll
        for (int r = 0; r < 4; ++r) h_old[r] = hg[(s0 + sl + r) * 100 + u];
    }
    __syncthreads();                             // zeroing done
    if (epi) {
#pragma unroll
        for (int r = 0; r < 4; ++r)
            hA[0][sl + r][u] = (unsigned short)f2bf1(h_old[r]);
    }
    __syncthreads();                             // buf0 ready

    // ---- gx row pointers (4 sample rows), g*50 as in-bounds offsets ----
    const u32* gp[4];
#pragma unroll
    for (int r = 0; r < 4; ++r) {
        const int sg = (s0 + sl + r < 128) ? (s0 + sl + r) : 0;
        gp[r] = gxR + (size_t)sg * CT * 150 + (uc >> 1);
    }

    u32 pfA[12], pfB[12];
#pragma unroll
    for (int i = 0; i < 12; ++i) { pfA[i] = 0; pfB[i] = 0; }
    if (epi) {
#pragma unroll
        for (int r = 0; r < 4; ++r)
#pragma unroll
            for (int g = 0; g < 3; ++g) {
                pfA[r*3+g] = gp[r][g * 50];
                if (CT > 1) pfB[r*3+g] = gp[r][150 + g * 50];
            }
    }
    int par = 0;

    auto stepf = [&](int t, u32* pf) {
        // A-fragments of h (bf16): m = col, k = ki*32 + quad*8 + j
        short8 a0 = *(const short8*)&hA[par][col][0  + quad * 8];
        short8 a1 = *(const short8*)&hA[par][col][32 + quad * 8];
        short8 a2 = *(const short8*)&hA[par][col][64 + quad * 8];
        short8 a3 = *(const short8*)&hA[par][col][96 + quad * 8];

        f32x4 accr = {0.f,0.f,0.f,0.f}, accz = {0.f,0.f,0.f,0.f}, accn = {0.f,0.f,0.f,0.f};
        accr = __builtin_amdgcn_mfma_f32_16x16x32_bf16(a0, bfr[0][0], accr, 0,0,0);
        accz = __builtin_amdgcn_mfma_f32_16x16x32_bf16(a0, bfr[1][0], accz, 0,0,0);
        accn = __builtin_amdgcn_mfma_f32_16x16x32_bf16(a0, bfr[2][0], accn, 0,0,0);
        accr = __builtin_amdgcn_mfma_f32_16x16x32_bf16(a1, bfr[0][1], accr, 0,0,0);
        accz = __builtin_amdgcn_mfma_f32_16x16x32_bf16(a1, bfr[1][1], accz, 0,0,0);
        accn = __builtin_amdgcn_mfma_f32_16x16x32_bf16(a1, bfr[2][1], accn, 0,0,0);
        accr = __builtin_amdgcn_mfma_f32_16x16x32_bf16(a2, bfr[0][2], accr, 0,0,0);
        accz = __builtin_amdgcn_mfma_f32_16x16x32_bf16(a2, bfr[1][2], accz, 0,0,0);
        accn = __builtin_amdgcn_mfma_f32_16x16x32_bf16(a2, bfr[2][2], accn, 0,0,0);
        accr = __builtin_amdgcn_mfma_f32_16x16x32_bf16(a3, bfr[0][3], accr, 0,0,0);
        accz = __builtin_amdgcn_mfma_f32_16x16x32_bf16(a3, bfr[1][3], accz, 0,0,0);
        accn = __builtin_amdgcn_mfma_f32_16x16x32_bf16(a3, bfr[2][3], accn, 0,0,0);

        u32 c[12];
#pragma unroll
        for (int i = 0; i < 12; ++i) c[i] = pf[i];
        if (epi && t + 2 < CT) {                 // prefetch distance 2
#pragma unroll
            for (int r = 0; r < 4; ++r)
#pragma unroll
                for (int g = 0; g < 3; ++g)
                    pf[r*3+g] = gp[r][(size_t)(t + 2) * 150 + g * 50];
        }

        if (epi) {
#pragma unroll
            for (int r = 0; r < 4; ++r) {
                const float gxr = odd ? bfhi(c[r*3+0]) : bflo(c[r*3+0]);
                const float gxz = odd ? bfhi(c[r*3+1]) : bflo(c[r*3+1]);
                const float gxn = odd ? bfhi(c[r*3+2]) : bflo(c[r*3+2]);
                const float rg = sigm(gxr + accr[r] + bh0);
                const float zg = sigm(gxz + accz[r] + bh1);
                const float ng = tanh_fast(gxn + rg * (accn[r] + bh2));
                h_old[r] = (1.f - zg) * ng + zg * h_old[r];
                hA[par ^ 1][sl + r][u] = (unsigned short)f2bf1(h_old[r]);
            }
        }
        __syncthreads();
        par ^= 1;
    };

    for (int t = 0; t < CT; t += 2) {
        stepf(t,     pfA);
        stepf(t + 1, pfB);
    }

    if (epi) {
#pragma unroll
        for (int r = 0; r < 4; ++r) hg[(s0 + sl + r) * 100 + u] = h_old[r];
    }

    if (last) {                                  // FC head from hA[par] (bf16 h)
        for (int idx = tid; idx < 800; idx += 448) {
            const int s = idx / 100, j = idx % 100;
            const float* fw = fc1_w + (size_t)j * 100;
            const u32* hr = (const u32*)&hA[par][s][0];
            float acc = fc1_b[j];
            for (int k2 = 0; k2 < 50; ++k2) {
                const u32 hv = hr[k2];
                acc += fw[2*k2] * bflo(hv) + fw[2*k2+1] * bfhi(hv);
            }
            out[(s0 + s) * 100 + j] = fmaxf(acc, 0.f);
        }
    }
}

// ---------------------------------------------------------------------------
extern "C" void kernel_launch(void* const* d_in, const int* in_sizes, int n_in,
                              void* d_out, int out_size, void* d_ws, size_t ws_size,
                              hipStream_t stream)
{
    const int*   neighbors = (const int*)  d_in[0];
    const int*   adj_row   = (const int*)  d_in[1];
    const int*   adj_col   = (const int*)  d_in[2];
    const float* adj_val   = (const float*)d_in[3];
    const float* emb       = (const float*)d_in[4];
    const float* gcn_w     = (const float*)d_in[5];
    const float* gcn_b     = (const float*)d_in[6];
    const float* w_ih      = (const float*)d_in[7];
    const float* w_hh      = (const float*)d_in[8];
    const float* b_ih      = (const float*)d_in[9];
    const float* b_hh      = (const float*)d_in[10];
    const float* fc1_w     = (const float*)d_in[11];
    const float* fc1_b     = (const float*)d_in[12];
    float* out = (float*)d_out;

    char* ws = (char*)d_ws;
    const size_t seq_bytes     = (size_t)128 * 1024 * 50 * 4;    // 26,214,400
    const size_t hg_bytes      = 128 * 100 * 4;                  // 51,200
    const size_t support_bytes = (size_t)128 * 1024 * 50 * 4;    // 26,214,400
    const size_t offs_bytes    = (size_t)128 * 1025 * 4;         // 524,800

    u32*   seq = (u32*)ws;
    float* hg  = (float*)(ws + seq_bytes);
    char*  rest = ws + seq_bytes + hg_bytes;
    const size_t rest_avail = ws_size - seq_bytes - hg_bytes;

    // Phase 1: support + CSR live in `rest`, dead before gx overwrites it.
    u32*  support = (u32*)rest;
    int*  offs    = (int*)(rest + support_bytes);
    int2* csr     = (int2*)(rest + support_bytes + offs_bytes);

    gcn_kernel<<<512, 256, 0, stream>>>(neighbors, emb, gcn_w, support);
    csr_build<<<128, 256, 0, stream>>>(adj_row, adj_col, adj_val, offs, csr);
    spmm_agg<<<dim3(205, 128), 256, 0, stream>>>(offs, csr, support, gcn_b, seq);

    const size_t gx_full = (size_t)128 * 1024 * 150 * 4;         // 78,643,200
    u32* gx = (u32*)rest;

    if (rest_avail >= gx_full) {
        gx_gemm0<<<1536, 256, 0, stream>>>(seq, w_ih, b_ih, gx, 0, 10, 1024);
        gru_mfma<<<16, 448, 0, stream>>>(gx, 1024, w_hh, b_hh, hg,
                                         fc1_w, fc1_b, out, 1, 1);
    } else {
        int CT = 512, ctl = 9;
        while (CT > 8 && (size_t)128 * CT * 150 * 4 > rest_avail) { CT >>= 1; --ctl; }
        const int nch = 1024 / CT;
        for (int c = 0; c < nch; ++c) {
            gx_gemm0<<<3 * (128 * CT / 256), 256, 0, stream>>>(seq, w_ih, b_ih, gx,
                                                               c * CT, ctl, CT);
            gru_mfma<<<16, 448, 0, stream>>>(gx, CT, w_hh, b_hh, hg,
                                             fc1_w, fc1_b, out,
                                             (c == 0) ? 1 : 0, (c == nch - 1) ? 1 : 0);
        }
    }
}